// Round 7
// baseline (177.537 us; speedup 1.0000x reference)
//
#include <hip/hip_runtime.h>

typedef __attribute__((ext_vector_type(8))) short short8;
typedef __attribute__((ext_vector_type(4))) float f32x4;
typedef __attribute__((ext_vector_type(4))) unsigned int u32x4;

#define NTOK 4096
#define DIM  256
#define P_STRIDE 72        // P row stride elems (144 B); chunk kc at pos = kc ^ (2*((r>>3)&1))
#define TILE_ELEMS 32768   // ushort elems per 64KB tile image (Ks 16384 | Kt 16384)

__device__ __forceinline__ unsigned pack2bf(float a, float b) {
  unsigned ua = __builtin_bit_cast(unsigned, a) + 0x8000u;
  unsigned ub = __builtin_bit_cast(unsigned, b) + 0x8000u;
  return __builtin_amdgcn_perm(ub, ua, 0x07060302u); // low=bf16(a), high=bf16(b)
}

// ---- prologue v2: single X read, LDS-staged transpose (verified R3) ------
__global__ __launch_bounds__(256, 4)
void prep_kernel(const float* __restrict__ X, unsigned short* __restrict__ Img) {
  __shared__ __align__(16) unsigned short rowbf[8 * 256];  // 4 KB bf16 stage
  const int b    = blockIdx.x & 3;
  const int sub  = blockIdx.x >> 2;   // 0..511
  const int t    = sub >> 3;
  const int part = sub & 7;
  const int tid  = threadIdx.x;
  const float* src = X + ((size_t)b * NTOK + t * 64 + part * 8) * DIM;
  unsigned short* dst = Img + ((size_t)(b * 64 + t)) * TILE_ELEMS;
  {
    const int r = tid >> 5;   // row within the 8-row slab
    const int c = tid & 31;   // 16B chunk within the row
    const float* s = src + r * DIM + c * 8;
    f32x4 f0 = *(const f32x4*)s;
    f32x4 f1 = *(const f32x4*)(s + 4);
    union { unsigned u[4]; u32x4 v; } p;
    p.u[0] = pack2bf(f0[0], f0[1]);
    p.u[1] = pack2bf(f0[2], f0[3]);
    p.u[2] = pack2bf(f1[0], f1[1]);
    p.u[3] = pack2bf(f1[2], f1[3]);
    const int gr = part * 8 + r;
    *(u32x4*)(dst + gr * 256 + ((c ^ (gr & 7)) << 3)) = p.v;
    *(u32x4*)(&rowbf[r * 256 + c * 8]) = p.v;
  }
  __syncthreads();
  {
    const int d = tid;        // one column per thread
    union { unsigned short s[8]; u32x4 v; } p;
    #pragma unroll
    for (int i = 0; i < 8; ++i) p.s[i] = rowbf[i * 256 + d];
    *(u32x4*)(dst + 16384 + part * 2048 + d * 8) = p.v;
  }
}

// ---- flash-attention v7: R4 data plan + 8-phase schedule (T3/T4/T5) ------
// Per 64-key tile, 4 phases; each phase:
//   {ds_read next subtile || issue DMA quarter} -> s_barrier -> lgkmcnt(0)
//   -> setprio(1) 8-MFMA cluster setprio(0) -> s_barrier
// ph0/ph1 = QK halves; ph2 = softmax VALU + PV(ks=0); ph3 = PV(ks=1) +
// P-store (after PV reads: R4's alias-pin win). Single vmcnt(0) at end of
// ph3 (staging has ~3 phases of flight). Data layout byte-identical to R4.
__global__ __launch_bounds__(512, 1)
void fa_kernel(const unsigned short* __restrict__ Img, float* __restrict__ Out) {
  __shared__ __align__(16) unsigned short ksb[2][16384];        // 64 KB
  __shared__ __align__(16) unsigned short ktb[2][16384];        // 64 KB
  __shared__ __align__(16) unsigned short pb[2][64 * P_STRIDE]; // 18 KB
  __shared__ float lbuf[64][4];                                 // 1 KB

  const int tid  = threadIdx.x;
  const int b    = blockIdx.x & 3;
  const int qblk = blockIdx.x >> 2;
  const int wave = tid >> 6;
  const int lane = tid & 63;
  const int ln   = lane & 15;
  const int quad = lane >> 4;
  const int swz  = ln & 7;
  const int qh   = wave & 1;
  const int role = wave >> 1;

  const unsigned short* imgb  = Img + (size_t)b * 64 * TILE_ELEMS;
  const char*           imgbc = (const char*)imgb;

  short8 aQ[2][8];
  #pragma unroll
  for (int s = 0; s < 2; ++s) {
    const unsigned short* qrow =
        imgb + (size_t)qblk * TILE_ELEMS + (qh * 32 + s * 16 + ln) * 256;
    #pragma unroll
    for (int ds = 0; ds < 8; ++ds)
      aQ[s][ds] = *(const short8*)(qrow + (((ds * 4 + quad) ^ swz) << 3));
  }

  f32x4 o[2][4];
  #pragma unroll
  for (int s = 0; s < 2; ++s)
    #pragma unroll
    for (int dt = 0; dt < 4; ++dt) o[s][dt] = (f32x4)(0.0f);
  float lrow[2][4] = {{0.f,0.f,0.f,0.f},{0.f,0.f,0.f,0.f}};

  const float c2 = 0.0901684400f;  // log2(e)/sqrt(256)

  // P write constants: kc = role*2 + (ln>>3); pos = kc ^ (2*(quad>>1))
  const int pwPos = ((role * 2 + (ln >> 3)) ^ ((quad >> 1) << 1)) << 3;
  const int pwCol = ln & 7;  // even lanes write dword covering cols (pwCol, pwCol+1)

  const bool dmaKs = wave < 4;
  const int  dmaQ  = wave & 3;
  const char* gK = imgbc + (size_t)dmaQ * 8192 + (size_t)lane * 16;

  if (dmaKs) {
    #pragma unroll
    for (int i = 0; i < 8; ++i)
      __builtin_amdgcn_global_load_lds(
          (const __attribute__((address_space(1))) unsigned*)(gK + i * 1024),
          (__attribute__((address_space(3))) unsigned*)(&ksb[0][dmaQ * 4096 + i * 512]),
          16, 0, 0);
  }
  __syncthreads();  // Ks(0) resident

  #pragma unroll 1
  for (int t = 0; t < 64; ++t) {
    const int buf = t & 1;
    const unsigned short* krow = &ksb[buf][(role * 16 + ln) * 256];
    const unsigned short* prd  = pb[buf ^ 1];
    const unsigned short* ktp  = ktb[buf ^ 1];
    const char* gNext = gK + (size_t)(t + 1) * 65536;       // Ks(t+1) src
    unsigned short* lNext = &ksb[buf ^ 1][dmaQ * 4096];     // Ks(t+1) dst
    const char* gKt = gK + (size_t)t * 65536 + 32768;       // Kt(t) src
    unsigned short* lKt = &ktb[buf][dmaQ * 4096];           // Kt(t) dst

    f32x4 sf0 = (f32x4)(0.0f), sf1 = (f32x4)(0.0f);

    // ================= ph0: QK ds0-3 =================
    {
      short8 bk[4];
      #pragma unroll
      for (int ds = 0; ds < 4; ++ds)
        bk[ds] = *(const short8*)(krow + (((ds * 4 + quad) ^ swz) << 3));
      if (dmaKs && t < 63) {
        #pragma unroll
        for (int i = 0; i < 4; ++i)
          __builtin_amdgcn_global_load_lds(
              (const __attribute__((address_space(1))) unsigned*)(gNext + i * 1024),
              (__attribute__((address_space(3))) unsigned*)(lNext + i * 512),
              16, 0, 0);
      }
      __builtin_amdgcn_s_barrier();
      asm volatile("s_waitcnt lgkmcnt(0)" ::: "memory");
      __builtin_amdgcn_sched_barrier(0);
      __builtin_amdgcn_s_setprio(1);
      #pragma unroll
      for (int ds = 0; ds < 4; ++ds) {
        sf0 = __builtin_amdgcn_mfma_f32_16x16x32_bf16(aQ[0][ds], bk[ds], sf0, 0, 0, 0);
        sf1 = __builtin_amdgcn_mfma_f32_16x16x32_bf16(aQ[1][ds], bk[ds], sf1, 0, 0, 0);
      }
      __builtin_amdgcn_s_setprio(0);
      __builtin_amdgcn_s_barrier();
    }

    // ================= ph1: QK ds4-7 =================
    {
      short8 bk[4];
      #pragma unroll
      for (int ds = 0; ds < 4; ++ds)
        bk[ds] = *(const short8*)(krow + ((((ds + 4) * 4 + quad) ^ swz) << 3));
      if (dmaKs) {
        if (t < 63) {
          #pragma unroll
          for (int i = 4; i < 8; ++i)
            __builtin_amdgcn_global_load_lds(
                (const __attribute__((address_space(1))) unsigned*)(gNext + i * 1024),
                (__attribute__((address_space(3))) unsigned*)(lNext + i * 512),
                16, 0, 0);
        }
      } else {
        #pragma unroll
        for (int i = 0; i < 4; ++i)
          __builtin_amdgcn_global_load_lds(
              (const __attribute__((address_space(1))) unsigned*)(gKt + i * 1024),
              (__attribute__((address_space(3))) unsigned*)(lKt + i * 512),
              16, 0, 0);
      }
      __builtin_amdgcn_s_barrier();
      asm volatile("s_waitcnt lgkmcnt(0)" ::: "memory");
      __builtin_amdgcn_sched_barrier(0);
      __builtin_amdgcn_s_setprio(1);
      #pragma unroll
      for (int ds = 0; ds < 4; ++ds) {
        sf0 = __builtin_amdgcn_mfma_f32_16x16x32_bf16(aQ[0][ds + 4], bk[ds], sf0, 0, 0, 0);
        sf1 = __builtin_amdgcn_mfma_f32_16x16x32_bf16(aQ[1][ds + 4], bk[ds], sf1, 0, 0, 0);
      }
      __builtin_amdgcn_s_setprio(0);
      __builtin_amdgcn_s_barrier();
    }

    // ============ ph2: softmax VALU + PV(ks=0) ============
    unsigned pd0[4], pd1[4];
    {
      #pragma unroll
      for (int j = 0; j < 4; ++j) {
        float p0 = __builtin_amdgcn_exp2f(sf0[j] * c2);
        float p1 = __builtin_amdgcn_exp2f(sf1[j] * c2);
        lrow[0][j] += p0;
        lrow[1][j] += p1;
        unsigned q0 = __builtin_bit_cast(unsigned, p0);
        unsigned q1 = __builtin_bit_cast(unsigned, p1);
        unsigned n0 = (unsigned)__builtin_amdgcn_mov_dpp((int)q0, 0xB1, 0xF, 0xF, true);
        unsigned n1 = (unsigned)__builtin_amdgcn_mov_dpp((int)q1, 0xB1, 0xF, 0xF, true);
        pd0[j] = pack2bf(__builtin_bit_cast(float, q0), __builtin_bit_cast(float, n0));
        pd1[j] = pack2bf(__builtin_bit_cast(float, q1), __builtin_bit_cast(float, n1));
      }
      short8 ap[2], bv[4];
      if (t > 0) {
        const int pos = quad ^ ((ln >> 3) << 1);   // ks = 0
        #pragma unroll
        for (int s = 0; s < 2; ++s)
          ap[s] = *(const short8*)(&prd[(qh * 32 + s * 16 + ln) * P_STRIDE + (pos << 3)]);
        const unsigned short* kb = ktp + quad * 2048 + (role * 64 + ln) * 8;
        #pragma unroll
        for (int dt = 0; dt < 4; ++dt) bv[dt] = *(const short8*)(kb + dt * 128);
      }
      if (!dmaKs) {
        #pragma unroll
        for (int i = 4; i < 8; ++i)
          __builtin_amdgcn_global_load_lds(
              (const __attribute__((address_space(1))) unsigned*)(gKt + i * 1024),
              (__attribute__((address_space(3))) unsigned*)(lKt + i * 512),
              16, 0, 0);
      }
      __builtin_amdgcn_s_barrier();
      asm volatile("s_waitcnt lgkmcnt(0)" ::: "memory");
      __builtin_amdgcn_sched_barrier(0);
      if (t > 0) {
        __builtin_amdgcn_s_setprio(1);
        #pragma unroll
        for (int s = 0; s < 2; ++s)
          #pragma unroll
          for (int dt = 0; dt < 4; ++dt)
            o[s][dt] = __builtin_amdgcn_mfma_f32_16x16x32_bf16(ap[s], bv[dt], o[s][dt], 0, 0, 0);
        __builtin_amdgcn_s_setprio(0);
      }
      __builtin_amdgcn_s_barrier();
    }

    // ============ ph3: PV(ks=1) + P-store ============
    {
      short8 ap[2], bv[4];
      if (t > 0) {
        const int pos = (4 + quad) ^ ((ln >> 3) << 1);  // ks = 1
        #pragma unroll
        for (int s = 0; s < 2; ++s)
          ap[s] = *(const short8*)(&prd[(qh * 32 + s * 16 + ln) * P_STRIDE + (pos << 3)]);
        const unsigned short* kb = ktp + (4 + quad) * 2048 + (role * 64 + ln) * 8;
        #pragma unroll
        for (int dt = 0; dt < 4; ++dt) bv[dt] = *(const short8*)(kb + dt * 128);
      }
      // P-store(t) AFTER the PV reads (alias-pin win from R4)
      if ((ln & 1) == 0) {
        unsigned short* pw = pb[buf];
        #pragma unroll
        for (int j = 0; j < 4; ++j) {
          const int r0 = qh * 32 + quad * 4 + j;
          *(unsigned*)(&pw[r0 * P_STRIDE + pwPos + pwCol]) = pd0[j];
          *(unsigned*)(&pw[(r0 + 16) * P_STRIDE + pwPos + pwCol]) = pd1[j];
        }
      }
      asm volatile("s_waitcnt vmcnt(0)" ::: "memory");  // staging: ~3 phases in flight
      __builtin_amdgcn_s_barrier();
      asm volatile("s_waitcnt lgkmcnt(0)" ::: "memory");
      __builtin_amdgcn_sched_barrier(0);
      if (t > 0) {
        __builtin_amdgcn_s_setprio(1);
        #pragma unroll
        for (int s = 0; s < 2; ++s)
          #pragma unroll
          for (int dt = 0; dt < 4; ++dt)
            o[s][dt] = __builtin_amdgcn_mfma_f32_16x16x32_bf16(ap[s], bv[dt], o[s][dt], 0, 0, 0);
        __builtin_amdgcn_s_setprio(0);
      }
      __builtin_amdgcn_s_barrier();
    }
  }

  __syncthreads();  // P(63), Kt(63) resident
  // final PV(63): pb[1], ktb[1]
  {
    const unsigned short* prd = pb[1];
    const unsigned short* ktp = ktb[1];
    #pragma unroll
    for (int ks = 0; ks < 2; ++ks) {
      const int pos = (ks * 4 + quad) ^ ((ln >> 3) << 1);
      short8 ap[2], bv[4];
      #pragma unroll
      for (int s = 0; s < 2; ++s)
        ap[s] = *(const short8*)(&prd[(qh * 32 + s * 16 + ln) * P_STRIDE + (pos << 3)]);
      const unsigned short* kb = ktp + (ks * 4 + quad) * 2048 + (role * 64 + ln) * 8;
      #pragma unroll
      for (int dt = 0; dt < 4; ++dt) bv[dt] = *(const short8*)(kb + dt * 128);
      #pragma unroll
      for (int s = 0; s < 2; ++s)
        #pragma unroll
        for (int dt = 0; dt < 4; ++dt)
          o[s][dt] = __builtin_amdgcn_mfma_f32_16x16x32_bf16(ap[s], bv[dt], o[s][dt], 0, 0, 0);
    }
  }

  // --- merge l across the 4 roles, divide, store ---
  #pragma unroll
  for (int off = 1; off < 16; off <<= 1)
    #pragma unroll
    for (int s = 0; s < 2; ++s)
      #pragma unroll
      for (int j = 0; j < 4; ++j)
        lrow[s][j] += __shfl_xor(lrow[s][j], off, 64);
  if (ln == 0) {
    #pragma unroll
    for (int s = 0; s < 2; ++s)
      #pragma unroll
      for (int j = 0; j < 4; ++j)
        lbuf[qh * 32 + s * 16 + quad * 4 + j][role] = lrow[s][j];
  }
  __syncthreads();

  #pragma unroll
  for (int s = 0; s < 2; ++s) {
    float* outp = Out + (size_t)(b * NTOK + qblk * 64 + qh * 32 + s * 16) * DIM + role * 64;
    #pragma unroll
    for (int j = 0; j < 4; ++j) {
      const int row = s * 16 + quad * 4 + j;
      f32x4 lv = *(const f32x4*)lbuf[qh * 32 + row];
      const float rl = 1.0f / (lv[0] + lv[1] + lv[2] + lv[3]);
      #pragma unroll
      for (int dt = 0; dt < 4; ++dt)
        outp[(size_t)(quad * 4 + j) * DIM + dt * 16 + ln] = o[s][dt][j] * rl;
    }
  }
}

extern "C" void kernel_launch(void* const* d_in, const int* in_sizes, int n_in,
                              void* d_out, int out_size, void* d_ws, size_t ws_size,
                              hipStream_t stream) {
  const float* X = (const float*)d_in[0];       // x: fp32 [4,4096,256]
  float* Out = (float*)d_out;                   // fp32 [4,4096,256]
  unsigned short* Img = (unsigned short*)d_ws;  // 16 MB bf16 tile images
  (void)in_sizes; (void)n_in; (void)out_size; (void)ws_size;
  hipLaunchKernelGGL(prep_kernel, dim3(2048), dim3(256), 0, stream, X, Img);
  hipLaunchKernelGGL(fa_kernel, dim3(256), dim3(512), 0, stream, Img, Out);
}

// Round 8
// 163.359 us; speedup vs baseline: 1.0868x; 1.0868x over previous
//
#include <hip/hip_runtime.h>

typedef __attribute__((ext_vector_type(8))) short short8;
typedef __attribute__((ext_vector_type(4))) float f32x4;
typedef __attribute__((ext_vector_type(4))) unsigned int u32x4;

#define NTOK 4096
#define DIM  256
#define P_STRIDE 72        // P row stride elems (144 B); chunk kc at pos = kc ^ (2*((r>>3)&1))
#define TILE_ELEMS 32768   // ushort elems per 64KB tile image (Ks 16384 | Kt 16384)

__device__ __forceinline__ unsigned pack2bf(float a, float b) {
  unsigned ua = __builtin_bit_cast(unsigned, a) + 0x8000u;
  unsigned ub = __builtin_bit_cast(unsigned, b) + 0x8000u;
  return __builtin_amdgcn_perm(ub, ua, 0x07060302u); // low=bf16(a), high=bf16(b)
}

// ---- prologue v2: single X read, LDS-staged transpose (verified R3) ------
__global__ __launch_bounds__(256, 4)
void prep_kernel(const float* __restrict__ X, unsigned short* __restrict__ Img) {
  __shared__ __align__(16) unsigned short rowbf[8 * 256];  // 4 KB bf16 stage
  const int b    = blockIdx.x & 3;
  const int sub  = blockIdx.x >> 2;   // 0..511
  const int t    = sub >> 3;
  const int part = sub & 7;
  const int tid  = threadIdx.x;
  const float* src = X + ((size_t)b * NTOK + t * 64 + part * 8) * DIM;
  unsigned short* dst = Img + ((size_t)(b * 64 + t)) * TILE_ELEMS;
  {
    const int r = tid >> 5;   // row within the 8-row slab
    const int c = tid & 31;   // 16B chunk within the row
    const float* s = src + r * DIM + c * 8;
    f32x4 f0 = *(const f32x4*)s;
    f32x4 f1 = *(const f32x4*)(s + 4);
    union { unsigned u[4]; u32x4 v; } p;
    p.u[0] = pack2bf(f0[0], f0[1]);
    p.u[1] = pack2bf(f0[2], f0[3]);
    p.u[2] = pack2bf(f1[0], f1[1]);
    p.u[3] = pack2bf(f1[2], f1[3]);
    const int gr = part * 8 + r;
    *(u32x4*)(dst + gr * 256 + ((c ^ (gr & 7)) << 3)) = p.v;
    *(u32x4*)(&rowbf[r * 256 + c * 8]) = p.v;
  }
  __syncthreads();
  {
    const int d = tid;        // one column per thread
    union { unsigned short s[8]; u32x4 v; } p;
    #pragma unroll
    for (int i = 0; i < 8; ++i) p.s[i] = rowbf[i * 256 + d];
    *(u32x4*)(dst + 16384 + part * 2048 + d * 8) = p.v;
  }
}

// ---- flash-attention v8: wave-specialized (4 QK + 4 PV waves) ------------
// QK wave (role=wave&3): keys role*16..+15 x ALL 64 q rows (K-read reuse 4x,
//   K LDS reads 64->32/CU-iter). Produces P cols + lrow sums.
// PV wave (role=wave&3): d-quarter role*64..+63 x all rows; V read ONCE from
//   L2-hot Kt image into reg dbuf (32KB/iter, no qh duplication; Kt LDS
//   staging deleted). P consumed via LDS (R4 layout, byte-identical image).
// SIMD pairing wave&3: one QK (VALU-heavy) + one PV (LDS-heavy) per SIMD.
// One __syncthreads/iter (R4-proven contract: drains DMA + V reg-loads).
// Register overlay: f32x4 u[32] = QK's aQ[4][8]  <->  PV's o[4][4]+V[2][2][4],
// all indices compile-time (rule #20).
#define FA_STEP(T, VLD, VUS)                                                   \
  {                                                                            \
    const int t_ = (T);                                                        \
    __syncthreads();                                                           \
    const int buf_ = t_ & 1;                                                   \
    if (!isQK) {                                                               \
      if (t_ < 63) {                                                           \
        const char* g = gK + (size_t)(t_ + 1) * 65536;                         \
        unsigned short* l = &ksb[buf_ ^ 1][role * 4096];                       \
        _Pragma("unroll")                                                      \
        for (int i = 0; i < 8; ++i)                                            \
          __builtin_amdgcn_global_load_lds(                                    \
              (const __attribute__((address_space(1))) unsigned*)(g + i*1024), \
              (__attribute__((address_space(3))) unsigned*)(l + i*512),        \
              16, 0, 0);                                                       \
      }                                                                        \
      {                                                                        \
        const unsigned short* vt = vtg + (size_t)t_ * TILE_ELEMS;              \
        _Pragma("unroll")                                                      \
        for (int ks = 0; ks < 2; ++ks)                                         \
          _Pragma("unroll")                                                    \
          for (int dt = 0; dt < 4; ++dt)                                       \
            u[(VLD) + ks * 4 + dt] = __builtin_bit_cast(f32x4,                 \
                *(const short8*)(vt + (ks * 4 + quad) * 2048 + dt * 128));     \
      }                                                                        \
      if (t_ > 0) {                                                            \
        const unsigned short* prd = pb[buf_ ^ 1];                              \
        _Pragma("unroll")                                                      \
        for (int ks = 0; ks < 2; ++ks) {                                       \
          const int pos = (ks * 4 + quad) ^ ((ln >> 3) << 1);                  \
          _Pragma("unroll")                                                    \
          for (int s = 0; s < 4; ++s) {                                        \
            short8 ap = *(const short8*)(                                      \
                &prd[(s * 16 + ln) * P_STRIDE + (pos << 3)]);                  \
            _Pragma("unroll")                                                  \
            for (int dt = 0; dt < 4; ++dt)                                     \
              u[s * 4 + dt] = __builtin_amdgcn_mfma_f32_16x16x32_bf16(         \
                  ap, __builtin_bit_cast(short8, u[(VUS) + ks * 4 + dt]),      \
                  u[s * 4 + dt], 0, 0, 0);                                     \
          }                                                                    \
        }                                                                      \
      }                                                                        \
    } else {                                                                   \
      const unsigned short* krow = &ksb[buf_][(role * 16 + ln) * 256];         \
      f32x4 sf[4];                                                             \
      _Pragma("unroll")                                                        \
      for (int s = 0; s < 4; ++s) sf[s] = (f32x4)(0.0f);                       \
      _Pragma("unroll")                                                        \
      for (int ds = 0; ds < 8; ++ds) {                                         \
        short8 bk = *(const short8*)(krow + (((ds * 4 + quad) ^ swz) << 3));   \
        _Pragma("unroll")                                                      \
        for (int s = 0; s < 4; ++s)                                            \
          sf[s] = __builtin_amdgcn_mfma_f32_16x16x32_bf16(                     \
              __builtin_bit_cast(short8, u[s * 8 + ds]), bk, sf[s], 0, 0, 0);  \
      }                                                                        \
      unsigned pd[4][4];                                                       \
      _Pragma("unroll")                                                        \
      for (int s = 0; s < 4; ++s)                                              \
        _Pragma("unroll")                                                      \
        for (int j = 0; j < 4; ++j) {                                          \
          float p0 = __builtin_amdgcn_exp2f(sf[s][j] * c2);                    \
          lrow[s][j] += p0;                                                    \
          unsigned q0 = __builtin_bit_cast(unsigned, p0);                      \
          unsigned n0 = (unsigned)__builtin_amdgcn_mov_dpp((int)q0, 0xB1,      \
                                                           0xF, 0xF, true);   \
          pd[s][j] = pack2bf(p0, __builtin_bit_cast(float, n0));               \
        }                                                                      \
      if ((ln & 1) == 0) {                                                     \
        unsigned short* pw = pb[buf_];                                         \
        _Pragma("unroll")                                                      \
        for (int s = 0; s < 4; ++s)                                            \
          _Pragma("unroll")                                                    \
          for (int j = 0; j < 4; ++j)                                          \
            *(unsigned*)(&pw[(s * 16 + quad * 4 + j) * P_STRIDE +              \
                             pwPos + pwCol]) = pd[s][j];                       \
      }                                                                        \
    }                                                                          \
  }

__global__ __launch_bounds__(512, 1)
void fa_kernel(const unsigned short* __restrict__ Img, float* __restrict__ Out) {
  __shared__ __align__(16) unsigned short ksb[2][16384];        // 64 KB Ks dbuf
  __shared__ __align__(16) unsigned short pb[2][64 * P_STRIDE]; // 18 KB P dbuf
  __shared__ float lbuf[64][4];                                 // 1 KB

  const int tid  = threadIdx.x;
  const int b    = blockIdx.x & 3;
  const int qblk = blockIdx.x >> 2;
  const int wave = tid >> 6;
  const int lane = tid & 63;
  const int ln   = lane & 15;
  const int quad = lane >> 4;
  const int swz  = ln & 7;
  const bool isQK = wave < 4;
  const int  role = wave & 3;  // QK: key-16 group; PV: d-quarter

  const unsigned short* imgb  = Img + (size_t)b * 64 * TILE_ELEMS;
  const char*           imgbc = (const char*)imgb;

  const float c2 = 0.0901684400f;  // log2(e)/sqrt(256)

  // P write constants (QK waves): kc = role*2 + (ln>>3); pos = kc ^ (2*(quad>>1))
  const int pwPos = ((role * 2 + (ln >> 3)) ^ ((quad >> 1) << 1)) << 3;
  const int pwCol = ln & 7;

  // PV: Ks DMA source (8KB quarter) and V-frag base in Kt image
  const char* gK = imgbc + (size_t)role * 8192 + (size_t)lane * 16;
  const unsigned short* vtg = imgb + 16384 + (size_t)(role * 64 + ln) * 8;

  float lrow[4][4] = {{0,0,0,0},{0,0,0,0},{0,0,0,0},{0,0,0,0}};

  // Register overlay: QK waves -> aQ[s][ds] = u[s*8+ds];
  //                   PV waves -> o[s][dt] = u[s*4+dt], V[set][ks][dt] = u[16+set*8+ks*4+dt]
  f32x4 u[32];
  if (isQK) {
    #pragma unroll
    for (int s = 0; s < 4; ++s) {
      const unsigned short* qrow =
          imgb + (size_t)qblk * TILE_ELEMS + (s * 16 + ln) * 256;
      #pragma unroll
      for (int ds = 0; ds < 8; ++ds)
        u[s * 8 + ds] = __builtin_bit_cast(f32x4,
            *(const short8*)(qrow + (((ds * 4 + quad) ^ swz) << 3)));
    }
  } else {
    #pragma unroll
    for (int i = 0; i < 16; ++i) u[i] = (f32x4)(0.0f);
    #pragma unroll
    for (int i = 0; i < 8; ++i)
      __builtin_amdgcn_global_load_lds(
          (const __attribute__((address_space(1))) unsigned*)(gK + i * 1024),
          (__attribute__((address_space(3))) unsigned*)(&ksb[0][role * 4096 + i * 512]),
          16, 0, 0);
  }

  FA_STEP(0, 16, 24);
  #pragma unroll 1
  for (int tt = 1; tt < 63; tt += 2) {
    FA_STEP(tt, 24, 16);
    FA_STEP(tt + 1, 16, 24);
  }
  FA_STEP(63, 24, 16);

  __syncthreads();  // drains V(63) reg loads; P(63) resident in pb[1]

  if (isQK) {
    // merge l over the 16 key-lanes of this role
    #pragma unroll
    for (int off = 1; off < 16; off <<= 1)
      #pragma unroll
      for (int s = 0; s < 4; ++s)
        #pragma unroll
        for (int j = 0; j < 4; ++j)
          lrow[s][j] += __shfl_xor(lrow[s][j], off, 64);
    if (ln == 0) {
      #pragma unroll
      for (int s = 0; s < 4; ++s)
        #pragma unroll
        for (int j = 0; j < 4; ++j)
          lbuf[s * 16 + quad * 4 + j][role] = lrow[s][j];
    }
  } else {
    // final PV(63): P from pb[1], V set = 24
    const unsigned short* prd = pb[1];
    #pragma unroll
    for (int ks = 0; ks < 2; ++ks) {
      const int pos = (ks * 4 + quad) ^ ((ln >> 3) << 1);
      #pragma unroll
      for (int s = 0; s < 4; ++s) {
        short8 ap = *(const short8*)(&prd[(s * 16 + ln) * P_STRIDE + (pos << 3)]);
        #pragma unroll
        for (int dt = 0; dt < 4; ++dt)
          u[s * 4 + dt] = __builtin_amdgcn_mfma_f32_16x16x32_bf16(
              ap, __builtin_bit_cast(short8, u[24 + ks * 4 + dt]),
              u[s * 4 + dt], 0, 0, 0);
      }
    }
  }
  __syncthreads();  // lbuf ready

  if (!isQK) {
    float* outB = Out + (size_t)(b * NTOK + qblk * 64) * DIM + role * 64;
    #pragma unroll
    for (int s = 0; s < 4; ++s) {
      #pragma unroll
      for (int j = 0; j < 4; ++j) {
        const int row = s * 16 + quad * 4 + j;
        f32x4 lv = *(const f32x4*)lbuf[row];
        const float rl = 1.0f / (lv[0] + lv[1] + lv[2] + lv[3]);
        #pragma unroll
        for (int dt = 0; dt < 4; ++dt)
          outB[(size_t)row * DIM + dt * 16 + ln] = u[s * 4 + dt][j] * rl;
      }
    }
  }
}

extern "C" void kernel_launch(void* const* d_in, const int* in_sizes, int n_in,
                              void* d_out, int out_size, void* d_ws, size_t ws_size,
                              hipStream_t stream) {
  const float* X = (const float*)d_in[0];       // x: fp32 [4,4096,256]
  float* Out = (float*)d_out;                   // fp32 [4,4096,256]
  unsigned short* Img = (unsigned short*)d_ws;  // 16 MB bf16 tile images
  (void)in_sizes; (void)n_in; (void)out_size; (void)ws_size;
  hipLaunchKernelGGL(prep_kernel, dim3(2048), dim3(256), 0, stream, X, Img);
  hipLaunchKernelGGL(fa_kernel, dim3(256), dim3(512), 0, stream, Img, Out);
}